// Round 6
// baseline (217.367 us; speedup 1.0000x reference)
//
#include <hip/hip_runtime.h>
#include <hip/hip_bf16.h>

constexpr int E     = 2048;   // edges
constexpr int NVARS = 512;    // variable nodes
constexpr int MAXP  = 24;     // table slots per column (max fan-in ~15)
constexpr int NBLK  = MAXP / 4;           // 6 four-entry blocks per column
constexpr int TB    = 8;      // batch rows per block in main kernel
constexpr int NT    = 512;    // threads per block in main kernel

// RNE float -> bf16 (kept in HIGH 16 bits).
__device__ __forceinline__ unsigned bf16hi(float f) {
    const unsigned uu = __float_as_uint(f);
    return (uu + 0x7FFFu + ((uu >> 16) & 1u)) & 0xFFFF0000u;
}
__device__ __forceinline__ unsigned pk2(float a, float b) {
    return (bf16hi(a) >> 16) | bf16hi(b);
}
__device__ __forceinline__ float bl(unsigned q) { return __uint_as_float(q << 16); }
__device__ __forceinline__ float bh(unsigned q) { return __uint_as_float(q & 0xFFFF0000u); }

// ---------------------------------------------------------------------------
// kA: scan skip mask (4 MB) -> var(e) and fused skip weight per column.
// Exactly one nonzero per column => unique writer. grid (8, 32), 256 thr.
// ---------------------------------------------------------------------------
__global__ __launch_bounds__(256)
void k_vsrc(const float* __restrict__ skip_mask,
            const float* __restrict__ llr_w,
            unsigned short* __restrict__ vsrc,
            float* __restrict__ skw)
{
    const int col = blockIdx.x * 256 + threadIdx.x;
    const int v0  = blockIdx.y * (NVARS / 32);     // 16-row stripe
    for (int v = v0; v < v0 + NVARS / 32; ++v) {
        const float m = skip_mask[(size_t)v * E + col];
        if (m != 0.0f) {
            vsrc[col] = (unsigned short)v;
            skw [col] = m * llr_w[(size_t)v * E + col];
        }
    }
}

// ---------------------------------------------------------------------------
// kB: single block. deg histogram over vsrc -> fan-in tot = deg(var)-1 ->
// nb = ceil(tot/4). Stable counting-sort of columns by nb (ballot/popcount
// ranking, fully deterministic) -> rankof[col], and meta[rank] =
// {skw, col | var<<11 | nb<<20}. Ranks grouped by nb kill wave divergence
// in fused_main.
// ---------------------------------------------------------------------------
__global__ __launch_bounds__(256)
void k_rank(const unsigned short* __restrict__ vsrc,
            const float* __restrict__ skw,
            unsigned short* __restrict__ rankof,
            float2* __restrict__ meta)
{
    __shared__ int deg[NVARS];
    __shared__ unsigned char nbArr[E];
    __shared__ int binCnt[8], binStart[8], running[8];
    __shared__ int waveCnt[4][8];

    const int tid  = threadIdx.x;
    const int lane = tid & 63;
    const int w    = tid >> 6;

    for (int i = tid; i < NVARS; i += 256) deg[i] = 0;
    if (tid < 8) { binCnt[tid] = 0; running[tid] = 0; }
    __syncthreads();
    for (int i = tid; i < E; i += 256) atomicAdd(&deg[vsrc[i]], 1);
    __syncthreads();
    for (int i = tid; i < E; i += 256) {
        int tot = deg[vsrc[i]] - 1;
        if (tot > MAXP) tot = MAXP;
        const int nb = (tot + 3) >> 2;
        nbArr[i] = (unsigned char)nb;
        atomicAdd(&binCnt[nb], 1);
    }
    __syncthreads();
    if (tid == 0) {
        int s = 0;
        for (int b = 0; b < 8; ++b) { binStart[b] = s; s += binCnt[b]; }
    }
    __syncthreads();

    for (int round = 0; round < E / 256; ++round) {
        const int c   = round * 256 + tid;
        const int myb = nbArr[c];
        int lanePre = 0;
        for (int b = 0; b < 8; ++b) {
            const unsigned long long m = __ballot(myb == b);
            if (b == myb) lanePre = __popcll(m & ((1ull << lane) - 1ull));
            if (lane == 0) waveCnt[w][b] = __popcll(m);
        }
        __syncthreads();
        int wavePre = 0;
        for (int w2 = 0; w2 < w; ++w2) wavePre += waveCnt[w2][myb];
        const int grank = binStart[myb] + running[myb] + wavePre + lanePre;
        rankof[c] = (unsigned short)grank;
        const int v = vsrc[c];
        meta[grank] = make_float2(skw[c],
                                  __int_as_float(c | (v << 11) | (myb << 20)));
        __syncthreads();
        if (tid < 8) {
            int s = 0;
            for (int w2 = 0; w2 < 4; ++w2) s += waveCnt[w2][tid];
            running[tid] += s;
        }
        __syncthreads();
    }
}

// ---------------------------------------------------------------------------
// kC: per column, find contributors = {e' : var(e')==var(col)} \ {col} by
// scanning vsrc (LDS, ascending e' = deterministic, matches mask row order),
// then gather odd_w + dropout gate, write rank-major packed table
// (uint4 block = 4 slots, coalesced across ranks) + pads + guard block.
// grid 32 x 64 threads.
// ---------------------------------------------------------------------------
__global__ __launch_bounds__(64)
void k_build(const unsigned short* __restrict__ vsrc,
             const unsigned short* __restrict__ rankof,
             const float* __restrict__ odd_w,
             const float* __restrict__ u,
             const float* __restrict__ logits,
             unsigned int* __restrict__ tbl)
{
    __shared__ unsigned short vs[E];
    __shared__ unsigned short mbuf[64][MAXP];

    const int tid = threadIdx.x;
    const int col = blockIdx.x * 64 + tid;

    for (int i = tid; i < E / 8; i += 64)
        ((uint4*)vs)[i] = ((const uint4*)vsrc)[i];
    __syncthreads();

    const unsigned v     = vs[col];
    const int      grank = rankof[col];

    int cnt = 0;
    const unsigned* vs32 = (const unsigned*)vs;
    for (int i2 = 0; i2 < E / 2; ++i2) {           // broadcast LDS reads
        const unsigned p = vs32[i2];
        const int e0 = 2 * i2, e1 = 2 * i2 + 1;
        if ((p & 0xFFFFu) == v && e0 != col && cnt < MAXP)
            mbuf[tid][cnt++] = (unsigned short)e0;
        if ((p >> 16) == v && e1 != col && cnt < MAXP)
            mbuf[tid][cnt++] = (unsigned short)e1;
    }

    const int nb = (cnt + 3) >> 2;
    for (int j = 0; j < nb * 4; ++j) {
        unsigned ent = 0u;
        if (j < cnt) {
            const int ep  = mbuf[tid][j];
            const float sig = 1.0f / (1.0f + __expf(-logits[ep]));
            const float z   = (u[ep] < sig) ? 1.0f : 0.0f;
            const float ww  = odd_w[(size_t)ep * E + col] * z;
            ent = bf16hi(ww) | (unsigned)ep;
        }
        tbl[((size_t)(j >> 2) * E + grank) * 4 + (j & 3)] = ent;
    }
    #pragma unroll
    for (int q = 0; q < 4; ++q)                     // guard block
        tbl[((size_t)nb * E + grank) * 4 + q] = 0u;
}

// tanh(0.5*clip(s,-10,10)) = (e^c - 1)/(e^c + 1)
__device__ __forceinline__ float tanh_half_clip(float s) {
    float c = fminf(fmaxf(s, -10.0f), 10.0f);
    float t = __expf(c);
    return (t - 1.0f) * __frcp_rn(t + 1.0f);
}

// ---------------------------------------------------------------------------
// Main fused kernel. TB=8 batch rows; x and llr staged in LDS as bf16,
// 8 rows per uint4 => ONE ds_read_b128 per gather entry. Table and meta are
// rank-major (coalesced loads, near-uniform nb per wave); only output stores
// and xs[] gathers use the true column. LDS = 40 KB -> 4 blocks/CU.
// ---------------------------------------------------------------------------
__global__ __launch_bounds__(NT, 8)
void fused_main(const float* __restrict__ x,          // [B, E]
                const float* __restrict__ llr,        // [B, NVARS]
                const unsigned int* __restrict__ tbl, // [NBLK+1][E] uint4 blocks
                const float2* __restrict__ meta,      // [E] rank-major
                float* __restrict__ out)
{
    __shared__ uint4 xs[E];        // 8 bf16 rows per column
    __shared__ uint4 ls[NVARS];    // 8 bf16 rows per variable

    const int b0 = blockIdx.x * TB;
    const int t  = threadIdx.x;

    {
        const float4* xr = (const float4*)(x + (size_t)b0 * E);
        const float4 r0 = xr[0 * (E / 4) + t];
        const float4 r1 = xr[1 * (E / 4) + t];
        const float4 r2 = xr[2 * (E / 4) + t];
        const float4 r3 = xr[3 * (E / 4) + t];
        const float4 r4 = xr[4 * (E / 4) + t];
        const float4 r5 = xr[5 * (E / 4) + t];
        const float4 r6 = xr[6 * (E / 4) + t];
        const float4 r7 = xr[7 * (E / 4) + t];
        xs[4 * t + 0] = make_uint4(pk2(r0.x, r1.x), pk2(r2.x, r3.x),
                                   pk2(r4.x, r5.x), pk2(r6.x, r7.x));
        xs[4 * t + 1] = make_uint4(pk2(r0.y, r1.y), pk2(r2.y, r3.y),
                                   pk2(r4.y, r5.y), pk2(r6.y, r7.y));
        xs[4 * t + 2] = make_uint4(pk2(r0.z, r1.z), pk2(r2.z, r3.z),
                                   pk2(r4.z, r5.z), pk2(r6.z, r7.z));
        xs[4 * t + 3] = make_uint4(pk2(r0.w, r1.w), pk2(r2.w, r3.w),
                                   pk2(r4.w, r5.w), pk2(r6.w, r7.w));
    }
    {
        const float* lr = llr + (size_t)b0 * NVARS;
        ls[t] = make_uint4(pk2(lr[t],             lr[NVARS + t]),
                           pk2(lr[2 * NVARS + t], lr[3 * NVARS + t]),
                           pk2(lr[4 * NVARS + t], lr[5 * NVARS + t]),
                           pk2(lr[6 * NVARS + t], lr[7 * NVARS + t]));
    }
    __syncthreads();

    #pragma unroll
    for (int k = 0; k < E / NT; ++k) {
        const int rk = k * NT + t;                  // rank (sorted by nb)
        const float2 mt = meta[rk];
        const int vc  = __float_as_int(mt.y);
        const int col = vc & 0x7FF;
        const int v   = (vc >> 11) & 0x1FF;
        const int nb  = vc >> 20;
        const float sk = mt.x;

        const uint4 lv = ls[v];
        float a0 = sk * bl(lv.x), a1 = sk * bh(lv.x);
        float a2 = sk * bl(lv.y), a3 = sk * bh(lv.y);
        float a4 = sk * bl(lv.z), a5 = sk * bh(lv.z);
        float a6 = sk * bl(lv.w), a7 = sk * bh(lv.w);

        const uint4* tq = (const uint4*)tbl + rk;   // coalesced (rank-major)
        uint4 g = tq[0];
        for (int ib = 0; ib < nb; ++ib) {
            const uint4 gn = tq[(size_t)(ib + 1) * E];   // guard at blk=nb
            #pragma unroll
            for (int q = 0; q < 4; ++q) {
                const unsigned ent = (q == 0) ? g.x : (q == 1) ? g.y
                                   : (q == 2) ? g.z : g.w;
                const float wv = __uint_as_float(ent & 0xFFFF0000u);
                const int   s  = (int)(ent & 0x7FFu);
                const uint4 xv = xs[s];                  // one ds_read_b128
                a0 += wv * bl(xv.x); a1 += wv * bh(xv.x);
                a2 += wv * bl(xv.y); a3 += wv * bh(xv.y);
                a4 += wv * bl(xv.z); a5 += wv * bh(xv.z);
                a6 += wv * bl(xv.w); a7 += wv * bh(xv.w);
            }
            g = gn;
        }

        const size_t o = (size_t)b0 * E + col;       // scattered (L2 absorbs)
        out[o]         = tanh_half_clip(a0);
        out[o + E]     = tanh_half_clip(a1);
        out[o + 2 * E] = tanh_half_clip(a2);
        out[o + 3 * E] = tanh_half_clip(a3);
        out[o + 4 * E] = tanh_half_clip(a4);
        out[o + 5 * E] = tanh_half_clip(a5);
        out[o + 6 * E] = tanh_half_clip(a6);
        out[o + 7 * E] = tanh_half_clip(a7);
    }
}

extern "C" void kernel_launch(void* const* d_in, const int* in_sizes, int n_in,
                              void* d_out, int out_size, void* d_ws, size_t ws_size,
                              hipStream_t stream) {
    const float* x        = (const float*)d_in[0];  // [B, E]
    const float* llr      = (const float*)d_in[1];  // [B, NVARS]
    const float* u        = (const float*)d_in[2];  // [E]
    const float* odd_w    = (const float*)d_in[3];  // [E, E]
    const float* llr_w    = (const float*)d_in[4];  // [NVARS, E]
    const float* logits   = (const float*)d_in[5];  // [E]
    // d_in[6] (o2e_mask) no longer needed: structure derived from skip mask.
    const float* skip_msk = (const float*)d_in[7];  // [NVARS, E]
    float* out = (float*)d_out;

    const int B = in_sizes[0] / E;                  // 16384

    // Workspace (~262 KB), 16B-aligned segments.
    char* wsb = (char*)d_ws;
    size_t off = 0;
    unsigned int*   tbl    = (unsigned int*)(wsb + off);   off += (size_t)(NBLK + 1) * E * 16; // 229376
    float2*         meta   = (float2*)(wsb + off);         off += (size_t)E * 8;               //  16384
    float*          skw    = (float*)(wsb + off);          off += (size_t)E * 4;               //   8192
    unsigned short* vsrc   = (unsigned short*)(wsb + off); off += (size_t)E * 2;               //   4096
    unsigned short* rankof = (unsigned short*)(wsb + off); off += (size_t)E * 2;               //   4096

    k_vsrc <<<dim3(E / 256, 32), dim3(256), 0, stream>>>(skip_msk, llr_w, vsrc, skw);
    k_rank <<<dim3(1),           dim3(256), 0, stream>>>(vsrc, skw, rankof, meta);
    k_build<<<dim3(E / 64),      dim3(64),  0, stream>>>(vsrc, rankof, odd_w, u, logits, tbl);

    fused_main<<<dim3(B / TB), dim3(NT), 0, stream>>>(x, llr, tbl, meta, out);
}